// Round 9
// baseline (125.622 us; speedup 1.0000x reference)
//
#include <hip/hip_runtime.h>
#include <hip/hip_bf16.h>

// INT4 group-quantized decode GEMM (M=64, K=8192, N=28672, GS=128).
// Round 9: R2 champion skeleton with ONE change — double-buffered lA/lB and
// a single barrier per chunk. Stage-phase of iter c+1 overlaps MFMA drain of
// iter c; barrier joins halve. Everything else byte-identical to R2 (122 us).

typedef float  f32x4 __attribute__((ext_vector_type(4)));
typedef float  f32x2 __attribute__((ext_vector_type(2)));
typedef short  s16x8 __attribute__((ext_vector_type(8)));
typedef int    i32x2 __attribute__((ext_vector_type(2)));
typedef int    i32x4 __attribute__((ext_vector_type(4)));

#define M_DIM 64
#define K_DIM 8192
#define N_DIM 28672
#define BN    64             // output cols per block
#define CK    128            // k per chunk == group_size
#define NCHUNK (K_DIM / CK)  // 64

// A in bf16 cell layout: cell (c, k8, m) = 8 k-contiguous bf16 of row m.
__device__ s16x8 g_wsa[NCHUNK * 1024];

static __device__ __forceinline__ short f2bf(float f) {
    return (short)__builtin_bit_cast(unsigned short, __float2bfloat16(f));
}

__global__ __launch_bounds__(256)
void prep_a_kernel(const float* __restrict__ x) {
    const int tid = threadIdx.x;
    const int c   = blockIdx.x >> 2;        // 0..63
    const int mb  = blockIdx.x & 3;
    const int k8  = tid & 15;
    const int m   = mb * 16 + (tid >> 4);
    const float* src = x + (size_t)m * K_DIM + c * CK + k8 * 8;
    f32x4 a = *(const f32x4*)src;
    f32x4 b = *(const f32x4*)(src + 4);
    s16x8 o;
    o[0] = f2bf(a[0]); o[1] = f2bf(a[1]); o[2] = f2bf(a[2]); o[3] = f2bf(a[3]);
    o[4] = f2bf(b[0]); o[5] = f2bf(b[1]); o[6] = f2bf(b[2]); o[7] = f2bf(b[3]);
    g_wsa[(size_t)c * 1024 + k8 * 64 + m] = o;
}

__global__ __launch_bounds__(512, 4)
void int4gemm_kernel(const int*   __restrict__ qw,
                     const float* __restrict__ sc,
                     const int*   __restrict__ qz,
                     const float* __restrict__ bias,
                     float*       __restrict__ out)
{
    // 16B cells: [buf][k8 0..15][idx 0..63], double-buffered
    __shared__ s16x8 lB[2][16 * 64];   // idx = col within block
    __shared__ s16x8 lA[2][16 * 64];   // idx = batch row m

    const int tid   = threadIdx.x;
    const int lane  = tid & 63;
    const int wave  = tid >> 6;      // 0..7
    const int nbase = blockIdx.x * BN;

    // B staging: thread owns cols (2p, 2p+1) x byte-rows q*4..q*4+3 (cell k8=q)
    const int p  = tid & 31;
    const int q  = tid >> 5;         // 0..15
    const int j0 = nbase + 2 * p;

    // MFMA coords: 8 waves = 2 (m-half) x 4 (n-tile)
    const int l15 = lane & 15;
    const int lk  = lane >> 4;       // 0..3
    const int mh  = wave >> 2;       // 0..1
    const int wn  = (wave & 3) * 16; // n-tile base

    f32x4 acc0 = (f32x4)0.0f, acc1 = (f32x4)0.0f;

    const int* qbase = qw + j0;
    const i32x4* wsa4 = (const i32x4*)g_wsa;

    // ---- pipeline registers ----
    i32x2 bvA[4], bvB[4], bvN[4];    // qweight: cur / +1 / +2
    i32x4 av0, av1;                  // A cells for next chunk to stage
    f32x2 sA, sB, sN;
    i32x2 zA, zB, zN;

    // prologue: B chunks 0,1; scales groups 0,1; A chunk 0
#pragma unroll
    for (int r = 0; r < 4; ++r) {
        bvA[r] = *(const i32x2*)(qbase + (size_t)(q * 4 + r) * N_DIM);
        bvB[r] = *(const i32x2*)(qbase + (size_t)(64 + q * 4 + r) * N_DIM);
    }
    sA = *(const f32x2*)(sc + j0);
    sB = *(const f32x2*)(sc + N_DIM + j0);
    zA = *(const i32x2*)(qz + j0);
    zB = *(const i32x2*)(qz + N_DIM + j0);
    av0 = wsa4[tid];
    av1 = wsa4[512 + tid];

#pragma unroll 2
    for (int c = 0; c < NCHUNK; ++c) {
        const int pb = c & 1;        // buffer parity for this chunk

        // ---- dequant current qweight quad (regs loaded 2 iters ago) ----
        const float s0 = sA.x, s1 = sA.y;
        const float o0 = -(float)zA.x * s0;
        const float o1 = -(float)zA.y * s1;
        s16x8 c0, c1;
#pragma unroll
        for (int r = 0; r < 4; ++r) {
            const int vx = bvA[r].x, vy = bvA[r].y;
            c0[2 * r]     = f2bf(fmaf((float)(vx & 15),        s0, o0));
            c0[2 * r + 1] = f2bf(fmaf((float)((vx >> 4) & 15), s0, o0));
            c1[2 * r]     = f2bf(fmaf((float)(vy & 15),        s1, o1));
            c1[2 * r + 1] = f2bf(fmaf((float)((vy >> 4) & 15), s1, o1));
        }

        // stage this chunk's tiles into buf[pb] (other parity than the
        // MFMA reads still draining from iter c-1 -> no WAR, no barrier)
        lB[pb][q * 64 + 2 * p]     = c0;
        lB[pb][q * 64 + 2 * p + 1] = c1;
        lA[pb][tid]       = __builtin_bit_cast(s16x8, av0);
        lA[pb][512 + tid] = __builtin_bit_cast(s16x8, av1);

        // prefetch: A for c+1, B + scales for c+2 (wrapped; tail loads unused)
        const int ca = (c + 1) & (NCHUNK - 1);
        av0 = wsa4[(size_t)ca * 1024 + tid];
        av1 = wsa4[(size_t)ca * 1024 + 512 + tid];
        const int cb = (c + 2) & (NCHUNK - 1);
#pragma unroll
        for (int r = 0; r < 4; ++r)
            bvN[r] = *(const i32x2*)(qbase + (size_t)(cb * 64 + q * 4 + r) * N_DIM);
        sN = *(const f32x2*)(sc + (size_t)cb * N_DIM + j0);
        zN = *(const i32x2*)(qz + (size_t)cb * N_DIM + j0);

        // ONE barrier per chunk: own lgkm drain (covers this iter's writes
        // AND last iter's MFMA reads), then join. VMEM prefetches in flight.
        asm volatile("s_waitcnt lgkmcnt(0)" ::: "memory");
        asm volatile("s_barrier" ::: "memory");
        __builtin_amdgcn_sched_barrier(0);

        // ---- MFMA: wave does 2 m-tiles x 1 n-tile x 4 k-slices ----
#pragma unroll
        for (int ks = 0; ks < 4; ++ks) {
            const int cell = (ks * 4 + lk) * 64;
            const s16x8 bfr = lB[pb][cell + wn + l15];
            const s16x8 af0 = lA[pb][cell + mh * 32 + l15];
            const s16x8 af1 = lA[pb][cell + mh * 32 + 16 + l15];
            acc0 = __builtin_amdgcn_mfma_f32_16x16x32_bf16(af0, bfr, acc0, 0, 0, 0);
            acc1 = __builtin_amdgcn_mfma_f32_16x16x32_bf16(af1, bfr, acc1, 0, 0, 0);
        }

        // rotate pipeline
#pragma unroll
        for (int r = 0; r < 4; ++r) { bvA[r] = bvB[r]; bvB[r] = bvN[r]; }
        sA = sB; sB = sN; zA = zB; zB = zN;
    }

    // ---- epilogue: bias + store (verified C layout) ----
    const int   ncol = nbase + wn + l15;
    const float bv   = bias[ncol];
    const int   m0   = mh * 32 + lk * 4;
#pragma unroll
    for (int jj = 0; jj < 4; ++jj) {
        out[(size_t)(m0 + jj) * N_DIM + ncol]      = acc0[jj] + bv;
        out[(size_t)(m0 + 16 + jj) * N_DIM + ncol] = acc1[jj] + bv;
    }
}

extern "C" void kernel_launch(void* const* d_in, const int* in_sizes, int n_in,
                              void* d_out, int out_size, void* d_ws, size_t ws_size,
                              hipStream_t stream) {
    const float* x    = (const float*)d_in[0];
    const int*   qw   = (const int*)d_in[1];
    const float* sc   = (const float*)d_in[2];
    const int*   qz   = (const int*)d_in[3];
    const float* bias = (const float*)d_in[4];
    float*       out  = (float*)d_out;

    prep_a_kernel<<<dim3(256), dim3(256), 0, stream>>>(x);
    int4gemm_kernel<<<dim3(N_DIM / BN), dim3(512), 0, stream>>>(qw, sc, qz, bias, out);
}

// Round 10
// 124.802 us; speedup vs baseline: 1.0066x; 1.0066x over previous
//
#include <hip/hip_runtime.h>
#include <hip/hip_bf16.h>

// INT4 group-quantized decode GEMM (M=64, K=8192, N=28672, GS=128).
// Round 10: EXACT R2 champion (122 us) + ONE change: XCD-chunked block
// swizzle. Default round-robin puts adjacent column-tiles on different XCDs,
// so each XCD L2 issues isolated 256-B HBM segments scattered over 114-KB
// rows. Swizzle nb=(bid&7)*56+(bid>>3) gives each XCD a contiguous 56-tile
// stripe -> per chunk, per row, 14-KB contiguous miss runs per XCD.

typedef float  f32x4 __attribute__((ext_vector_type(4)));
typedef float  f32x2 __attribute__((ext_vector_type(2)));
typedef short  s16x8 __attribute__((ext_vector_type(8)));
typedef int    i32x2 __attribute__((ext_vector_type(2)));
typedef int    i32x4 __attribute__((ext_vector_type(4)));

#define M_DIM 64
#define K_DIM 8192
#define N_DIM 28672
#define BN    64             // output cols per block
#define CK    128            // k per chunk == group_size
#define NCHUNK (K_DIM / CK)  // 64
#define NB     (N_DIM / BN)  // 448 = 8 XCDs * 56

// A in bf16 cell layout: cell (c, k8, m) = 8 k-contiguous bf16 of row m.
__device__ s16x8 g_wsa[NCHUNK * 1024];

static __device__ __forceinline__ short f2bf(float f) {
    return (short)__builtin_bit_cast(unsigned short, __float2bfloat16(f));
}

__global__ __launch_bounds__(256)
void prep_a_kernel(const float* __restrict__ x) {
    const int tid = threadIdx.x;
    const int c   = blockIdx.x >> 2;        // 0..63
    const int mb  = blockIdx.x & 3;
    const int k8  = tid & 15;
    const int m   = mb * 16 + (tid >> 4);
    const float* src = x + (size_t)m * K_DIM + c * CK + k8 * 8;
    f32x4 a = *(const f32x4*)src;
    f32x4 b = *(const f32x4*)(src + 4);
    s16x8 o;
    o[0] = f2bf(a[0]); o[1] = f2bf(a[1]); o[2] = f2bf(a[2]); o[3] = f2bf(a[3]);
    o[4] = f2bf(b[0]); o[5] = f2bf(b[1]); o[6] = f2bf(b[2]); o[7] = f2bf(b[3]);
    g_wsa[(size_t)c * 1024 + k8 * 64 + m] = o;
}

__global__ __launch_bounds__(512, 4)
void int4gemm_kernel(const int*   __restrict__ qw,
                     const float* __restrict__ sc,
                     const int*   __restrict__ qz,
                     const float* __restrict__ bias,
                     float*       __restrict__ out)
{
    // 16B cells: [k8 0..15][idx 0..63]
    __shared__ s16x8 lB[16 * 64];   // idx = col within block
    __shared__ s16x8 lA[16 * 64];   // idx = batch row m

    const int tid   = threadIdx.x;
    const int lane  = tid & 63;
    const int wave  = tid >> 6;      // 0..7

    // XCD-chunked swizzle: blocks 8k+j (hardware RR -> XCD j) map to
    // column-tile j*56+k, so each XCD owns a contiguous 56-tile stripe.
    const int bid   = blockIdx.x;
    const int nb    = (bid & 7) * (NB / 8) + (bid >> 3);
    const int nbase = nb * BN;

    // B staging: thread owns cols (2p, 2p+1) x byte-rows q*4..q*4+3 (cell k8=q)
    const int p  = tid & 31;
    const int q  = tid >> 5;         // 0..15
    const int j0 = nbase + 2 * p;

    // MFMA coords: 8 waves = 2 (m-half) x 4 (n-tile)
    const int l15 = lane & 15;
    const int lk  = lane >> 4;       // 0..3
    const int mh  = wave >> 2;       // 0..1
    const int wn  = (wave & 3) * 16; // n-tile base

    f32x4 acc0 = (f32x4)0.0f, acc1 = (f32x4)0.0f;

    const int* qbase = qw + j0;
    const i32x4* wsa4 = (const i32x4*)g_wsa;

    // ---- pipeline registers ----
    i32x2 bvA[4], bvB[4], bvN[4];    // qweight: cur / +1 / +2
    i32x4 av0, av1;                  // A cells for next chunk to stage
    f32x2 sA, sB, sN;
    i32x2 zA, zB, zN;

    // prologue: B chunks 0,1; scales groups 0,1; A chunk 0
#pragma unroll
    for (int r = 0; r < 4; ++r) {
        bvA[r] = *(const i32x2*)(qbase + (size_t)(q * 4 + r) * N_DIM);
        bvB[r] = *(const i32x2*)(qbase + (size_t)(64 + q * 4 + r) * N_DIM);
    }
    sA = *(const f32x2*)(sc + j0);
    sB = *(const f32x2*)(sc + N_DIM + j0);
    zA = *(const i32x2*)(qz + j0);
    zB = *(const i32x2*)(qz + N_DIM + j0);
    av0 = wsa4[tid];
    av1 = wsa4[512 + tid];

    for (int c = 0; c < NCHUNK; ++c) {
        // ---- dequant current qweight quad (regs loaded 2 iters ago) ----
        const float s0 = sA.x, s1 = sA.y;
        const float o0 = -(float)zA.x * s0;
        const float o1 = -(float)zA.y * s1;
        s16x8 c0, c1;
#pragma unroll
        for (int r = 0; r < 4; ++r) {
            const int vx = bvA[r].x, vy = bvA[r].y;
            c0[2 * r]     = f2bf(fmaf((float)(vx & 15),        s0, o0));
            c0[2 * r + 1] = f2bf(fmaf((float)((vx >> 4) & 15), s0, o0));
            c1[2 * r]     = f2bf(fmaf((float)(vy & 15),        s1, o1));
            c1[2 * r + 1] = f2bf(fmaf((float)((vy >> 4) & 15), s1, o1));
        }

        // barrier1: previous MFMA phase done reading LDS (no vmem drain)
        asm volatile("s_barrier" ::: "memory");

        // stage this chunk's tiles
        lB[q * 64 + 2 * p]          = c0;
        lB[q * 64 + 2 * p + 1]      = c1;
        lA[tid]       = __builtin_bit_cast(s16x8, av0);
        lA[512 + tid] = __builtin_bit_cast(s16x8, av1);

        // prefetch: A for c+1, B + scales for c+2 (wrapped; tail loads unused)
        const int ca = (c + 1) & (NCHUNK - 1);
        av0 = wsa4[(size_t)ca * 1024 + tid];
        av1 = wsa4[(size_t)ca * 1024 + 512 + tid];
        const int cb = (c + 2) & (NCHUNK - 1);
#pragma unroll
        for (int r = 0; r < 4; ++r)
            bvN[r] = *(const i32x2*)(qbase + (size_t)(cb * 64 + q * 4 + r) * N_DIM);
        sN = *(const f32x2*)(sc + (size_t)cb * N_DIM + j0);
        zN = *(const i32x2*)(qz + (size_t)cb * N_DIM + j0);

        // barrier2: LDS writes visible; vmem prefetches stay in flight
        asm volatile("s_waitcnt lgkmcnt(0)" ::: "memory");
        asm volatile("s_barrier" ::: "memory");
        __builtin_amdgcn_sched_barrier(0);

        // ---- MFMA: wave does 2 m-tiles x 1 n-tile x 4 k-slices ----
#pragma unroll
        for (int ks = 0; ks < 4; ++ks) {
            const int cell = (ks * 4 + lk) * 64;
            const s16x8 bfr = lB[cell + wn + l15];
            const s16x8 af0 = lA[cell + mh * 32 + l15];
            const s16x8 af1 = lA[cell + mh * 32 + 16 + l15];
            acc0 = __builtin_amdgcn_mfma_f32_16x16x32_bf16(af0, bfr, acc0, 0, 0, 0);
            acc1 = __builtin_amdgcn_mfma_f32_16x16x32_bf16(af1, bfr, acc1, 0, 0, 0);
        }

        // rotate pipeline
#pragma unroll
        for (int r = 0; r < 4; ++r) { bvA[r] = bvB[r]; bvB[r] = bvN[r]; }
        sA = sB; sB = sN; zA = zB; zB = zN;
    }

    // ---- epilogue: bias + store (verified C layout) ----
    const int   ncol = nbase + wn + l15;
    const float bv   = bias[ncol];
    const int   m0   = mh * 32 + lk * 4;
#pragma unroll
    for (int jj = 0; jj < 4; ++jj) {
        out[(size_t)(m0 + jj) * N_DIM + ncol]      = acc0[jj] + bv;
        out[(size_t)(m0 + 16 + jj) * N_DIM + ncol] = acc1[jj] + bv;
    }
}

extern "C" void kernel_launch(void* const* d_in, const int* in_sizes, int n_in,
                              void* d_out, int out_size, void* d_ws, size_t ws_size,
                              hipStream_t stream) {
    const float* x    = (const float*)d_in[0];
    const int*   qw   = (const int*)d_in[1];
    const float* sc   = (const float*)d_in[2];
    const int*   qz   = (const int*)d_in[3];
    const float* bias = (const float*)d_in[4];
    float*       out  = (float*)d_out;

    prep_a_kernel<<<dim3(256), dim3(256), 0, stream>>>(x);
    int4gemm_kernel<<<dim3(NB), dim3(512), 0, stream>>>(qw, sc, qz, bias, out);
}